// Round 3
// baseline (80.881 us; speedup 1.0000x reference)
//
#include <hip/hip_runtime.h>
#include <hip/hip_bf16.h>
#include <string.h>

constexpr int B_ = 8;
constexpr int N_ = 2048;
constexpr int FIN = 128;
constexpr int FOUT = 64;
constexpr float ALPHA_ = 0.2f;
constexpr float NEG_INF_ = -9000000000000000.0f;

typedef __attribute__((ext_vector_type(8))) short bf16x8;
typedef __attribute__((ext_vector_type(4))) float f32x4;

static __device__ __forceinline__ unsigned short f2bf(float x) {
  unsigned int u = __float_as_uint(x);
  unsigned int r = u + 0x7fffu + ((u >> 16) & 1u);
  return (unsigned short)(r >> 16);
}

// Counted barrier: only drain LDS ops (lgkmcnt); leave global loads/stores
// (vmcnt) in flight across the barrier. Rule #18: sched_barrier fences so
// hipcc can't hoist dependent ops across the inline-asm waitcnt.
#define SBAR()                                         \
  do {                                                 \
    __builtin_amdgcn_sched_barrier(0);                 \
    asm volatile("s_waitcnt lgkmcnt(0)" ::: "memory"); \
    __builtin_amdgcn_s_barrier();                      \
    __builtin_amdgcn_sched_barrier(0);                 \
  } while (0)

// ---------------- Kernel 1: Wh^T (bf16) + si/sj (f32, exact) ----------------
__global__ __launch_bounds__(256) void k_wh(
    const float* __restrict__ h, const float* __restrict__ W,
    const float* __restrict__ a, unsigned short* __restrict__ WhT,
    float* __restrict__ si, float* __restrict__ sj) {
  const int lane = threadIdx.x & 63;
  const int wv = threadIdx.x >> 6;
  const int grow0 = blockIdx.x * 32 + wv * 8;  // b*N + n, 8 rows
  const int f = lane;
  float acc[8] = {0.f, 0.f, 0.f, 0.f, 0.f, 0.f, 0.f, 0.f};
  const float* hp = h + (size_t)grow0 * FIN;
#pragma unroll 4
  for (int k = 0; k < FIN; k += 4) {
    float w0 = W[k * FOUT + f];
    float w1 = W[(k + 1) * FOUT + f];
    float w2 = W[(k + 2) * FOUT + f];
    float w3 = W[(k + 3) * FOUT + f];
#pragma unroll
    for (int r = 0; r < 8; ++r) {
      float4 hv = *(const float4*)(hp + r * FIN + k);
      acc[r] = fmaf(hv.x, w0, acc[r]);
      acc[r] = fmaf(hv.y, w1, acc[r]);
      acc[r] = fmaf(hv.z, w2, acc[r]);
      acc[r] = fmaf(hv.w, w3, acc[r]);
    }
  }
  const float a1 = a[f], a2 = a[FOUT + f];
#pragma unroll
  for (int r = 0; r < 8; ++r) {
    float p1 = acc[r] * a1;
    float p2 = acc[r] * a2;
#pragma unroll
    for (int off = 32; off; off >>= 1) {
      p1 += __shfl_xor(p1, off);
      p2 += __shfl_xor(p2, off);
    }
    if (lane == 0) {
      si[grow0 + r] = p1;
      sj[grow0 + r] = p2;
    }
  }
  const int b = grow0 >> 11;
  const int n0 = grow0 & (N_ - 1);
  __align__(16) unsigned short u[8];
#pragma unroll
  for (int r = 0; r < 8; ++r) u[r] = f2bf(acc[r]);
  *(bf16x8*)&WhT[(((size_t)(b * FOUT + f)) << 11) + n0] = *(const bf16x8*)u;
}

// ---------------- Kernel 2: adj -> bitmasks ----------------
__global__ __launch_bounds__(256) void k_pack(
    const int* __restrict__ adj, unsigned long long* __restrict__ mask_rm,
    unsigned int* __restrict__ mask_t) {
  const int lane = threadIdx.x & 63;
  const int wv = threadIdx.x >> 6;
  const int r = blockIdx.x * 4 + wv;
  const int* row = adj + (size_t)r * N_;
  unsigned int wacc = 0;
#pragma unroll
  for (int it = 0; it < 32; ++it) {
    int v = row[it * 64 + lane];
    unsigned long long bm = __ballot(v > 0);
    if (lane == 0) mask_rm[r * 32 + it] = bm;
    wacc |= ((unsigned int)(v > 0)) << it;
  }
  mask_t[r * 64 + lane] = wacc;
}

// ---------------- Kernel 3: per-row softmax stats ----------------
__global__ __launch_bounds__(256) void k_stats(
    const unsigned int* __restrict__ mask_t, const float* __restrict__ si,
    const float* __restrict__ sj, float* __restrict__ mrow,
    float* __restrict__ rrow) {
  const int lane = threadIdx.x & 63;
  const int wv = threadIdx.x >> 6;
  const int row = blockIdx.x * 4 + wv;  // b*N + i
  const int b = row >> 11;
  const int i = row & (N_ - 1);
  const unsigned int w32 = mask_t[i * 64 + lane];
  const float* sjb = sj + ((size_t)b << 11);
  float sjv[32];
  float M = -3.0e38f;
#pragma unroll
  for (int it = 0; it < 32; ++it) {
    sjv[it] = sjb[it * 64 + lane];
    if ((w32 >> it) & 1u) M = fmaxf(M, sjv[it]);
  }
#pragma unroll
  for (int off = 32; off; off >>= 1) M = fmaxf(M, __shfl_xor(M, off));
  const float siv = si[row];
  const float e0 = siv + M;
  const float m = e0 > 0.f ? e0 : ALPHA_ * e0;
  float s = 0.f;
#pragma unroll
  for (int it = 0; it < 32; ++it) {
    float e = siv + sjv[it];
    float v = e > 0.f ? e : ALPHA_ * e;
    float p = __expf(v - m);
    s += ((w32 >> it) & 1u) ? p : 0.f;
  }
#pragma unroll
  for (int off = 32; off; off >>= 1) s += __shfl_xor(s, off);
  if (lane == 0) {
    mrow[row] = m;
    rrow[row] = 1.f / s;
  }
}

// ---------------- Kernel 4: att write + h' = att @ Wh via MFMA ----------------
// Counted-lgkm barriers: att stores + B prefetch loads stay in flight (vmcnt
// never drained in the loop); only LDS deps synchronize waves.
constexpr int TI = 32;
constexpr int CH = 128;

__global__ __launch_bounds__(512) void k_main(
    const unsigned short* __restrict__ WhT,
    const unsigned long long* __restrict__ mask_rm,
    const float* __restrict__ si, const float* __restrict__ sjg,
    const float* __restrict__ mrow, const float* __restrict__ rrow,
    float* __restrict__ att_out, float* __restrict__ h_out) {
  __shared__ __align__(16) unsigned short A_lds[TI * CH];    // 8 KB, swizzled
  __shared__ __align__(16) unsigned short Bt_lds[FOUT * CH]; // 16 KB, swizzled
  __shared__ float s_sj[N_];                                 // 8 KB
  __shared__ float s_si[TI], s_m[TI], s_r[TI];

  // XCD-aware swizzle: 512 blocks, XCD x <-> batch x (WhT/sj/mask L2-resident)
  const int bid = blockIdx.x;
  const int swz = (bid & 7) * 64 + (bid >> 3);
  const int b = swz >> 6;
  const int i0 = (swz & 63) * TI;

  const int tid = threadIdx.x;
  const int lane = tid & 63;
  const int wv = tid >> 6;
  const int rt = wv >> 2;  // 0..1 : 16-row tile
  const int ct = wv & 3;   // 0..3 : 16-col tile

  const unsigned char* maskb = (const unsigned char*)mask_rm;
  char* Ab = (char*)A_lds;
  char* Bb = (char*)Bt_lds;

  const int r = tid >> 4;  // 0..31: att row this thread computes / B row pair
  const int q = tid & 15;  // 8-col unit within chunk

  // prefetch B-tile for chunk 0 into regs
  bf16x8 bv[2];
#pragma unroll
  for (int p = 0; p < 2; ++p)
    bv[p] = *(const bf16x8*)&WhT[(((size_t)(b * FOUT + r + p * 32)) << 11) + q * 8];

  for (int x = tid; x < N_; x += 512) s_sj[x] = sjg[(b << 11) + x];
  if (tid < TI) {
    s_si[tid] = si[(b << 11) + i0 + tid];
    s_m[tid] = mrow[(b << 11) + i0 + tid];
    s_r[tid] = rrow[(b << 11) + i0 + tid];
  }
  __syncthreads();

  f32x4 acc = {0.f, 0.f, 0.f, 0.f};

  for (int t = 0; t < N_ / CH; ++t) {
    const int j0 = t * CH;
    // ---- phase A: ds_write B, issue next-chunk prefetch, compute+write att ----
#pragma unroll
    for (int p = 0; p < 2; ++p) {
      const int fr = r + p * 32;  // 0..63
      *(bf16x8*)(Bb + ((fr * 256 + q * 16) ^ ((fr & 7) << 4))) = bv[p];
    }
    {  // prefetch B-tile for chunk t+1 (wraps at end; no wait here)
      const int jn = ((t + 1) & (N_ / CH - 1)) * CH;
#pragma unroll
      for (int p = 0; p < 2; ++p)
        bv[p] = *(const bf16x8*)&WhT[(((size_t)(b * FOUT + r + p * 32)) << 11) + jn + q * 8];
    }
    {
      const int jb = j0 + q * 8;
      const unsigned int mbits = maskb[(i0 + r) * 256 + (jb >> 3)];
      const float sir = s_si[r], mr = s_m[r], rr = s_r[r];
      const float4 sj0 = *(const float4*)&s_sj[jb];
      const float4 sj1 = *(const float4*)&s_sj[jb + 4];
      const float sjl[8] = {sj0.x, sj0.y, sj0.z, sj0.w, sj1.x, sj1.y, sj1.z, sj1.w};
      float av[8];
#pragma unroll
      for (int e = 0; e < 8; ++e) {
        float ev = sir + sjl[e];
        float v = ev > 0.f ? ev : ALPHA_ * ev;
        float p = __expf(v - mr) * rr;
        av[e] = ((mbits >> e) & 1u) ? p : 0.f;
      }
      float* ao = att_out + (((size_t)((b << 11) + i0 + r)) << 11) + jb;
      *(float4*)ao = make_float4(av[0], av[1], av[2], av[3]);
      *(float4*)(ao + 4) = make_float4(av[4], av[5], av[6], av[7]);
      __align__(16) unsigned short u[8];
#pragma unroll
      for (int e = 0; e < 8; ++e) u[e] = f2bf(av[e]);
      *(bf16x8*)(Ab + ((r * 256 + q * 16) ^ ((r & 7) << 4))) = *(const bf16x8*)u;
    }
    SBAR();
    // ---- phase B: MFMA over the 4 k-steps of this chunk ----
    {
      const int arow = rt * 16 + (lane & 15);
      const int brow = ct * 16 + (lane & 15);
      const int kb = (lane >> 4) * 16;
      const int axor = (arow & 7) << 4;
      const int bxor = (brow & 7) << 4;
#pragma unroll
      for (int ks = 0; ks < 4; ++ks) {
        bf16x8 af = *(const bf16x8*)(Ab + ((arow * 256 + ks * 64 + kb) ^ axor));
        bf16x8 bvv = *(const bf16x8*)(Bb + ((brow * 256 + ks * 64 + kb) ^ bxor));
        acc = __builtin_amdgcn_mfma_f32_16x16x32_bf16(af, bvv, acc, 0, 0, 0);
      }
    }
    SBAR();
  }

  // ---- epilogue: elu + store (C/D layout: col=lane&15, row=(lane>>4)*4+reg) ----
  const int colb = ct * 16 + (lane & 15);
  const int rowb = i0 + rt * 16 + ((lane >> 4) << 2);
#pragma unroll
  for (int qq = 0; qq < 4; ++qq) {
    float x = acc[qq];
    float o = x > 0.f ? x : __expf(x) - 1.f;
    h_out[(((size_t)((b << 11) + rowb + qq)) << 6) + colb] = o;
  }
}

extern "C" void kernel_launch(void* const* d_in, const int* in_sizes, int n_in,
                              void* d_out, int out_size, void* d_ws, size_t ws_size,
                              hipStream_t stream) {
  const float* h = (const float*)d_in[0];
  const int* adj = (const int*)d_in[1];
  const float* W = (const float*)d_in[2];
  const float* a = (const float*)d_in[3];

  float* out = (float*)d_out;
  float* h_out = out;                             // B*N*FOUT
  float* att_out = out + (size_t)B_ * N_ * FOUT;  // B*N*N

  unsigned short* WhT = (unsigned short*)d_ws;                       // 2 MB
  float* si = (float*)((char*)d_ws + (size_t)2 * 1024 * 1024);       // 64 KB
  float* sj = si + B_ * N_;                                          // 64 KB
  float* mrow = sj + B_ * N_;                                        // 64 KB
  float* rrow = mrow + B_ * N_;                                      // 64 KB
  unsigned long long* mask_rm = (unsigned long long*)(rrow + B_ * N_);  // 512 KB
  unsigned int* mask_t = (unsigned int*)((char*)mask_rm + (size_t)N_ * 32 * 8);  // 512 KB

  k_wh<<<B_ * N_ / 32, 256, 0, stream>>>(h, W, a, WhT, si, sj);
  k_pack<<<N_ / 4, 256, 0, stream>>>(adj, mask_rm, mask_t);
  k_stats<<<B_ * N_ / 4, 256, 0, stream>>>(mask_t, si, sj, mrow, rrow);
  k_main<<<B_ * N_ / TI, 512, 0, stream>>>(WhT, mask_rm, si, sj, mrow, rrow,
                                           att_out, h_out);
}